// Round 2
// baseline (174.339 us; speedup 1.0000x reference)
//
#include <hip/hip_runtime.h>
#include <math.h>

typedef unsigned long long u64;
typedef _Float16 f16x8 __attribute__((ext_vector_type(8)));
typedef float f32x16 __attribute__((ext_vector_type(16)));

#define N_PTS 12000
#define KNN 16
#define QB 16                            // queries per block (M rows 0..15 real, 16..31 zero-pad)
#define NWAVES 8                         // waves per block (512 threads)
#define NGROUPS32 (N_PTS / 32)           // 375 candidate groups of 32
#define TAU_PTS 2048
#define TAU_GROUPS32 (TAU_PTS / 32)      // 64
#define CAP 384                          // survivor capacity; 6 offers/lane
#define MARGIN 0.08f                     // > 2*m, m = f16 d2 error bound ~0.032
#define EVICT_KEY ((u64)0x7F400000u << 32)  // > any real key and > init sentinels

// ---------------------------------------------------------------------------
// Kernel 1: encoders. feats = tanh(x@Wf+bf); coords = tanh(x@Wl+bl) fp32+f16;
// sq = |coords|^2. One wave per row.
// ---------------------------------------------------------------------------
__global__ __launch_bounds__(256) void encoder_kernel(
    const float* __restrict__ x, const float* __restrict__ Wf, const float* __restrict__ bf,
    const float* __restrict__ Wl, const float* __restrict__ bl,
    float* __restrict__ feats, float* __restrict__ coords, _Float16* __restrict__ coords_h,
    float* __restrict__ sq)
{
  const int wave = threadIdx.x >> 6;
  const int lane = threadIdx.x & 63;
  const int i = blockIdx.x * 4 + wave;
  if (i >= N_PTS) return;
  float xv = x[i * 64 + lane];
  float accf = bf[lane];
  float accc = bl[lane & 15];
  #pragma unroll
  for (int k = 0; k < 64; ++k) {
    float xk = __shfl(xv, k);
    accf = fmaf(xk, Wf[k * 64 + lane], accf);
    accc = fmaf(xk, Wl[k * 16 + (lane & 15)], accc);
  }
  feats[i * 64 + lane] = tanhf(accf);
  float c = tanhf(accc);
  float cc = (lane < 16) ? c * c : 0.0f;
  cc += __shfl_xor(cc, 1);
  cc += __shfl_xor(cc, 2);
  cc += __shfl_xor(cc, 4);
  cc += __shfl_xor(cc, 8);
  if (lane < 16) {
    coords[i * 16 + lane] = c;
    coords_h[i * 16 + lane] = (_Float16)c;
  }
  if (lane == 0) sq[i] = cc;
}

// ---------------------------------------------------------------------------
// u64-key helpers. Keys (f32bits(d2)<<32)|j unique; sentinels (0x7F00000t<<32)
// exceed any real key; ~0ull matches no slot.
// ---------------------------------------------------------------------------
__device__ __forceinline__ void ins6(u64 key, u64* k6, u64& kmax) {
  const u64 om = (key < kmax) ? kmax : ~0ull;
  #pragma unroll
  for (int t = 0; t < 6; ++t)
    k6[t] = (k6[t] == om) ? key : k6[t];
  u64 a = k6[0] > k6[1] ? k6[0] : k6[1];
  u64 b = k6[2] > k6[3] ? k6[2] : k6[3];
  u64 c = k6[4] > k6[5] ? k6[4] : k6[5];
  a = a > b ? a : b;
  kmax = a > c ? a : c;
}

__device__ __forceinline__ void ins8(u64 key, u64* k8, u64& kmax) {
  const u64 om = (key < kmax) ? kmax : ~0ull;
  #pragma unroll
  for (int t = 0; t < 8; ++t)
    k8[t] = (k8[t] == om) ? key : k8[t];
  u64 a = k8[0] > k8[1] ? k8[0] : k8[1];
  u64 b = k8[2] > k8[3] ? k8[2] : k8[3];
  u64 c = k8[4] > k8[5] ? k8[4] : k8[5];
  u64 d = k8[6] > k8[7] ? k8[6] : k8[7];
  a = a > b ? a : b;
  c = c > d ? c : d;
  kmax = a > c ? a : c;
}

__device__ __forceinline__ u64 shflx_u64(u64 v, int off) {
  int lo = __shfl_xor((int)(unsigned)v, off);
  int hi = __shfl_xor((int)(unsigned)(v >> 32), off);
  return ((u64)(unsigned)hi << 32) | (unsigned)lo;
}

__device__ __forceinline__ u64 minbfly(u64 m) {
  #pragma unroll
  for (int off = 32; off >= 1; off >>= 1) {
    u64 o = shflx_u64(m, off);
    m = (o < m) ? o : m;
  }
  return m;
}

// compare-and-swap for the 6-element per-lane sort network
#define CAS6(i, j) { const u64 a_ = k6[i], b_ = k6[j]; const bool sw_ = a_ > b_; \
                     k6[i] = sw_ ? b_ : a_; k6[j] = sw_ ? a_ : b_; }

// ---------------------------------------------------------------------------
// Kernel 2: 32x32x16-MFMA KNN + gaussian aggregation + fused output GEMM.
// Block = 16 queries (A rows 0..15 real, 16..31 zero), 8 waves. Per 32-cand
// group: one full-wave coalesced B load (1KB/instr) + one
// mfma_f32_32x32x16_f16 (K=16 exact) -> 512 useful dots.
// C layout (m74/m101-verified): col=lane&31, row=(reg&3)+8*(reg>>2)+4*(lane>>5);
// regs r=0..7 (rows<16) are the valid checks per lane.
//
// C-INIT TRICK: accumulator is preloaded with -0.5*(sqi+sqj) so the MFMA
// emits acc = dot - 0.5*(sqi+sqj) = -0.5*d2a directly. No per-iter re-zero
// (16 v_mov saved), no post-MFMA add: gate is acc >= -0.5*tau (hoisted).
// Dead regs 8..15 (A rows 16..31 are zero) accumulate nothing; init once.
//
// Phase A: per-lane maxima of acc -> 64 disjoint 32-pt-subset cell minima
//   (d2 = max(-2*acc,0)) via LDS atomicMin; tau = 16th order stat + MARGIN.
//   Self excluded behind a wave-uniform g==g_self scalar branch (only blocks
//   with qbase<2048 ever hit it). SOUND: 16 smallest cells are 16 distinct
//   points => bound >= true 16th.
// Phase B: full scan, gate acc >= -0.5*tau, push u16 index (wave-uniform
//   __any skip for empty clusters).
// Phase C: exact fp32 re-score (ceil(nread/64) iters, 6-slot u64 tables,
//   <=6 offers/lane: no eviction -> exact); 12-CAS sort network per lane,
//   then 16 branchless extraction rounds: f32 butterfly + ballot + readlane
//   (results SGPR-resident) + conditional pop-shift on the owner lane.
//   Gather loop issues all 16 coalesced feats loads back-to-back; __expf.
// Epilogue: block GEMM out = concat(feats,agg)@Wo + bo, float4 LDS reads.
// Only failure mode: survivor overflow -> flag -> fixup recomputes row+out.
// ---------------------------------------------------------------------------
__global__ __launch_bounds__(512) void knn_agg_kernel(
    const float* __restrict__ coords, const _Float16* __restrict__ coords_h,
    const float* __restrict__ sq, const float* __restrict__ feats,
    const float* __restrict__ Wo, const float* __restrict__ bo,
    float* __restrict__ out, int* __restrict__ flags)
{
  __shared__ unsigned short sbuf[QB][CAP];   // 12288 B
  __shared__ int scnt[QB];                   //    64 B
  __shared__ unsigned colminS[QB][64];       //  4096 B
  __shared__ float taugS[QB];                //    64 B
  __shared__ __align__(16) float featS[QB][64];  // 4096 B
  __shared__ __align__(16) float aggS[QB][64];   // 4096 B

  const int tid = threadIdx.x;       // 0..511
  const int lane = tid & 63;
  const int wave = tid >> 6;         // 0..7
  const int qbase = blockIdx.x * QB;
  const int mcol = lane & 31;        // A row / B col
  const int half = lane >> 5;        // k-half (0: k=0..7, 1: k=8..15)

  if (tid < QB) scnt[tid] = 0;
  #pragma unroll
  for (int t = tid; t < QB * 64; t += 512)
    ((unsigned*)colminS)[t] = 0x7F800000u;   // +INF bits

  // A fragment: A[m=lane&31][k=half*8+j]; rows >=16 zero (padding)
  f16x8 afrag = {0, 0, 0, 0, 0, 0, 0, 0};
  if (mcol < QB) {
    const uint4 u = *(const uint4*)((const char*)coords_h + (qbase + mcol) * 32 + half * 16);
    afrag = __builtin_bit_cast(f16x8, u);
  }
  // rows handled by this lane: row(r) = (r>>2)*8 + 4*half + (r&3), r=0..7
  float sqi8[8], nhsqi8[8];
  #pragma unroll
  for (int blk = 0; blk < 2; ++blk) {
    const float4 v = *(const float4*)&sq[qbase + blk * 8 + 4 * half];
    sqi8[blk * 4 + 0] = v.x; sqi8[blk * 4 + 1] = v.y;
    sqi8[blk * 4 + 2] = v.z; sqi8[blk * 4 + 3] = v.w;
  }
  #pragma unroll
  for (int r = 0; r < 8; ++r) nhsqi8[r] = -0.5f * sqi8[r];

  f32x16 acc;
  #pragma unroll
  for (int t = 0; t < 16; ++t) acc[t] = 0.0f;   // regs 8..15 stay 0 forever

  __syncthreads();   // scnt + colminS init visible

  // ===================== Phase A: sample scan -> cell minima =================
  const int g_self = qbase >> 5;     // the only group that can contain self
  float lmax8[8] = {-INFINITY, -INFINITY, -INFINITY, -INFINITY,
                    -INFINITY, -INFINITY, -INFINITY, -INFINITY};
  for (int g = wave; g < TAU_GROUPS32; g += NWAVES) {
    const int j0 = g * 32;
    const uint4 u = *(const uint4*)((const char*)coords_h + (j0 + mcol) * 32 + half * 16);
    const f16x8 bfrag = __builtin_bit_cast(f16x8, u);
    const float sqj = sq[j0 + mcol];
    #pragma unroll
    for (int r = 0; r < 8; ++r) acc[r] = fmaf(-0.5f, sqj, nhsqi8[r]);
    acc = __builtin_amdgcn_mfma_f32_32x32x16_f16(afrag, bfrag, acc, 0, 0, 0);
    if (g == g_self) {               // wave-uniform, almost never taken
      #pragma unroll
      for (int r = 0; r < 8; ++r) {
        const int row = (r >> 2) * 8 + 4 * half + (r & 3);
        if (j0 + mcol == qbase + row) acc[r] = -INFINITY;  // exclude self
      }
    }
    #pragma unroll
    for (int r = 0; r < 8; ++r) lmax8[r] = fmaxf(lmax8[r], acc[r]);
  }
  {
    const int cell = mcol * 2 + (wave >> 2);  // 64 disjoint 32-pt subsets
    #pragma unroll
    for (int r = 0; r < 8; ++r) {
      const int row = (r >> 2) * 8 + 4 * half + (r & 3);
      atomicMin(&colminS[row][cell], __float_as_uint(fmaxf(-2.0f * lmax8[r], 0.0f)));
    }
  }
  __syncthreads();

  // tau per query: 16th order stat of the 64 cell minima (bitonic, lane 15)
  #pragma unroll
  for (int s = 0; s < 2; ++s) {
    const int q = wave * 2 + s;
    float v = __uint_as_float(colminS[q][lane]);
    #pragma unroll
    for (int k = 2; k <= 64; k <<= 1) {
      #pragma unroll
      for (int st = k >> 1; st >= 1; st >>= 1) {
        const float o = __shfl_xor(v, st);
        const bool keepMin = (((lane & st) == 0) == ((lane & k) == 0));
        const float mn = fminf(v, o), mx = fmaxf(v, o);
        v = keepMin ? mn : mx;
      }
    }
    const float tq = __shfl(v, 15) + MARGIN;   // sound gate
    if (lane == 0) taugS[q] = tq;
  }
  __syncthreads();

  // gate in transformed space: d2a <= tau  <=>  acc[r] >= -0.5*tau
  float nht8[8];
  #pragma unroll
  for (int r = 0; r < 8; ++r)
    nht8[r] = -0.5f * taugS[(r >> 2) * 8 + 4 * half + (r & 3)];

  // ===================== Phase B: full MFMA scan, push survivors ============
  #pragma unroll 2
  for (int g = wave; g < NGROUPS32; g += NWAVES) {
    const int j0 = g * 32;
    const uint4 u = *(const uint4*)((const char*)coords_h + (j0 + mcol) * 32 + half * 16);
    const f16x8 bfrag = __builtin_bit_cast(f16x8, u);
    const float sqj = sq[j0 + mcol];
    #pragma unroll
    for (int r = 0; r < 8; ++r) acc[r] = fmaf(-0.5f, sqj, nhsqi8[r]);
    acc = __builtin_amdgcn_mfma_f32_32x32x16_f16(afrag, bfrag, acc, 0, 0, 0);
    #pragma unroll
    for (int r = 0; r < 8; ++r) {
      const bool pass = acc[r] >= nht8[r];   // self passes; filtered in Phase C
      if (__any(pass)) {                     // wave-uniform skip (SALU branch)
        if (pass) {
          const int row = (r >> 2) * 8 + 4 * half + (r & 3);
          const int p = atomicAdd(&scnt[row], 1);
          if (p < CAP) sbuf[row][p] = (unsigned short)(j0 + mcol);
        }
      }
    }
  }
  __syncthreads();

  // ===================== Phase C: exact fp32 re-score + top-16 ===============
  #pragma unroll
  for (int s = 0; s < 2; ++s) {
    const int lq = wave * 2 + s;         // query-in-block 0..15
    const int qg = qbase + lq;           // global query id
    const int cq = scnt[lq];
    const int nread = (cq < CAP) ? cq : CAP;
    const int nit = (nread + 63) >> 6;   // only scan occupied slots

    float ci[16];
    {
      const float4* cp = (const float4*)(coords + qg * 16);
      *(float4*)&ci[0] = cp[0]; *(float4*)&ci[4] = cp[1];
      *(float4*)&ci[8] = cp[2]; *(float4*)&ci[12] = cp[3];
    }
    const float sqiq = sq[qg];

    u64 k6[6];
    #pragma unroll
    for (int t = 0; t < 6; ++t) k6[t] = ((u64)(0x7F000000u + t) << 32);
    u64 kmax6 = ((u64)0x7F000005u << 32);

    for (int t = 0; t < nit; ++t) {      // <=6 offers/lane: no eviction
      const int idx = t * 64 + lane;
      u64 key = ~0ull;
      if (idx < nread) {
        const int jj = sbuf[lq][idx];
        if (jj != qg) {
          const float4* cp = (const float4*)(coords + jj * 16);
          float cj[16];
          *(float4*)&cj[0]  = cp[0]; *(float4*)&cj[4]  = cp[1];
          *(float4*)&cj[8]  = cp[2]; *(float4*)&cj[12] = cp[3];
          float dot = 0.0f;
          #pragma unroll
          for (int d = 0; d < 16; ++d) dot = fmaf(ci[d], cj[d], dot);
          const float d2 = fmaxf(fmaf(-2.0f, dot, sqiq + sq[jj]), 0.0f);
          key = ((u64)__float_as_uint(d2) << 32) | (unsigned)jj;
        }
      }
      ins6(key, k6, kmax6);
    }

    // ---- per-lane ascending sort (12-CAS optimal network for 6 elems) ----
    CAS6(0,5) CAS6(1,3) CAS6(2,4)
    CAS6(1,2) CAS6(3,4)
    CAS6(0,3) CAS6(2,5)
    CAS6(0,1) CAS6(2,3) CAS6(4,5)
    CAS6(1,2) CAS6(3,4)

    // ---- extraction: 16 branchless rounds, f32 butterfly + pop-shift ----
    float dmin = __uint_as_float((unsigned)(k6[0] >> 32));
    int jmin = (int)(unsigned)(k6[0] & 0xFFFFFFFFull);

    float dv[16]; int jv[16];            // wave-uniform -> SGPR-resident
    #pragma unroll
    for (int r = 0; r < KNN; ++r) {
      float m = dmin;
      #pragma unroll
      for (int off = 32; off >= 1; off >>= 1)
        m = fminf(m, __shfl_xor(m, off));
      const u64 bal = __ballot(dmin == m);
      const int owner = __ffsll((unsigned long long)bal) - 1;
      jv[r] = __builtin_amdgcn_readlane(jmin, owner);
      dv[r] = __uint_as_float(__builtin_amdgcn_readfirstlane(__float_as_uint(m)));
      const bool me = (lane == owner);   // pop the owner's head (sorted list)
      k6[0] = me ? k6[1] : k6[0];
      k6[1] = me ? k6[2] : k6[1];
      k6[2] = me ? k6[3] : k6[2];
      k6[3] = me ? k6[4] : k6[3];
      k6[4] = me ? k6[5] : k6[4];
      k6[5] = me ? EVICT_KEY : k6[5];
      dmin = __uint_as_float((unsigned)(k6[0] >> 32));
      jmin = (int)(unsigned)(k6[0] & 0xFFFFFFFFull);
    }

    // ---- aggregation: all 16 coalesced gathers issue back-to-back ----
    // sentinel rounds: dv huge -> __expf(-dv)=0, jv=0 -> harmless gather
    float aggv = 0.0f;
    #pragma unroll
    for (int r = 0; r < KNN; ++r)
      aggv = fmaf(__expf(-dv[r]), feats[jv[r] * 64 + lane], aggv);

    aggS[lq][lane] = aggv;
    featS[lq][lane] = feats[qg * 64 + lane];
    if (lane == 0) flags[qg] = (cq > CAP);
  }

  // ===================== Epilogue: fused out GEMM (16 rows/block) ============
  __syncthreads();
  const int row = tid >> 5;        // 0..15
  const int c2 = (tid & 31) * 2;   // cols c2, c2+1 (float2)
  float acc0 = bo[c2], acc1 = bo[c2 + 1];
  #pragma unroll
  for (int f0 = 0; f0 < 64; f0 += 4) {
    const float4 fv = *(const float4*)&featS[row][f0];
    const float4 av = *(const float4*)&aggS[row][f0];
    #pragma unroll
    for (int u = 0; u < 4; ++u) {
      const float fvu = (u == 0) ? fv.x : (u == 1) ? fv.y : (u == 2) ? fv.z : fv.w;
      const float avu = (u == 0) ? av.x : (u == 1) ? av.y : (u == 2) ? av.z : av.w;
      const float2 w0 = *(const float2*)&Wo[(f0 + u) * 64 + c2];
      const float2 w1 = *(const float2*)&Wo[(64 + f0 + u) * 64 + c2];
      acc0 = fmaf(fvu, w0.x, acc0); acc0 = fmaf(avu, w1.x, acc0);
      acc1 = fmaf(fvu, w0.y, acc1); acc1 = fmaf(avu, w1.y, acc1);
    }
  }
  const int orow = qbase + row;
  *(float2*)&out[orow * 64 + c2] = make_float2(acc0, acc1);
}

// ---------------------------------------------------------------------------
// Kernel 2b: exact fallback for flagged (overflowed) queries — expected zero.
// Recomputes the full row: exact KNN + aggregation + fused out row.
// ---------------------------------------------------------------------------
__global__ __launch_bounds__(256) void knn_fixup_kernel(
    const float* __restrict__ coords, const float* __restrict__ sq,
    const float* __restrict__ feats, const int* __restrict__ flags,
    const float* __restrict__ Wo, const float* __restrict__ bo,
    float* __restrict__ out)
{
  const int wave = threadIdx.x >> 6;
  const int lane = threadIdx.x & 63;
  const int i = blockIdx.x * 4 + wave;
  if (i >= N_PTS) return;
  if (!flags[i]) return;
  float ci[16];
  #pragma unroll
  for (int d = 0; d < 16; ++d) ci[d] = coords[i * 16 + d];
  const float sqi = sq[i];

  u64 k8a[8], k8b[8], kmaxA, kmaxB;
  #pragma unroll
  for (int t = 0; t < 8; ++t) {
    k8a[t] = ((u64)(0x7F000000u + t) << 32);
    k8b[t] = ((u64)(0x7F000000u + t) << 32);
  }
  kmaxA = ((u64)0x7F000007u << 32);
  kmaxB = ((u64)0x7F000007u << 32);

  const int niter = (N_PTS + 63) / 64;  // 188
  for (int t = 0; t < niter; ++t) {
    const int j = t * 64 + lane;
    float4 c0 = make_float4(0,0,0,0), c1 = c0, c2 = c0, c3 = c0;
    float sqj = 0.0f;
    if (j < N_PTS) {
      const float4* cp = (const float4*)(coords + j * 16);
      c0 = cp[0]; c1 = cp[1]; c2 = cp[2]; c3 = cp[3];
      sqj = sq[j];
    }
    float dot = ci[0]*c0.x + ci[1]*c0.y + ci[2]*c0.z + ci[3]*c0.w
              + ci[4]*c1.x + ci[5]*c1.y + ci[6]*c1.z + ci[7]*c1.w
              + ci[8]*c2.x + ci[9]*c2.y + ci[10]*c2.z + ci[11]*c2.w
              + ci[12]*c3.x + ci[13]*c3.y + ci[14]*c3.z + ci[15]*c3.w;
    float d2 = fmaxf(fmaf(-2.0f, dot, sqi + sqj), 0.0f);
    const unsigned hi = (j == i || j >= N_PTS) ? 0xFFFFFFFFu : __float_as_uint(d2);
    const u64 key = ((u64)hi << 32) | (unsigned)j;
    if (t & 1) ins8(key, k8a, kmaxA);
    else       ins8(key, k8b, kmaxB);
  }

  u64 tab[16];
  #pragma unroll
  for (int t = 0; t < 8; ++t) { tab[t] = k8a[t]; tab[8 + t] = k8b[t]; }
  u64 lmin = tab[0];
  #pragma unroll
  for (int t = 1; t < 16; ++t) lmin = (tab[t] < lmin) ? tab[t] : lmin;

  float aggv = 0.0f;
  u64 T16 = 0;
  for (int r = 0; r < KNN; ++r) {
    const u64 m = minbfly(lmin);
    if (lmin == m) {
      #pragma unroll
      for (int t = 0; t < 16; ++t) tab[t] = (tab[t] == m) ? ~0ull : tab[t];
      lmin = tab[0];
      #pragma unroll
      for (int t = 1; t < 16; ++t) lmin = (tab[t] < lmin) ? tab[t] : lmin;
    }
    const unsigned hi = (unsigned)(m >> 32);
    const bool ok = hi < 0x7F000000u;
    const float w = ok ? expf(-__uint_as_float(hi)) : 0.0f;
    const int jj = ok ? (int)(unsigned)(m & 0xFFFFFFFFull) : 0;
    aggv = fmaf(w, feats[jj * 64 + lane], aggv);
    T16 = m;
  }

  if (__any((kmaxA < T16) || (kmaxB < T16))) {
    aggv = 0.0f;
    u64 prev = 0;
    for (int r = 0; r < KNN; ++r) {
      u64 best = ~0ull;
      for (int j = lane; j < N_PTS; j += 64) {
        float dot = 0.0f;
        #pragma unroll
        for (int d = 0; d < 16; ++d) dot = fmaf(ci[d], coords[j * 16 + d], dot);
        const float d2 = fmaxf(fmaf(-2.0f, dot, sqi + sq[j]), 0.0f);
        const unsigned hi = (j == i) ? 0xFFFFFFFFu : __float_as_uint(d2);
        const u64 key = ((u64)hi << 32) | (unsigned)j;
        const bool cand = (r == 0) || (key > prev);
        if (cand && key < best) best = key;
      }
      const u64 m = minbfly(best);
      prev = m;
      const unsigned hi = (unsigned)(m >> 32);
      const bool ok = hi < 0x7F000000u;
      const float w = ok ? expf(-__uint_as_float(hi)) : 0.0f;
      const int jj = ok ? (int)(unsigned)(m & 0xFFFFFFFFull) : 0;
      aggv = fmaf(w, feats[jj * 64 + lane], aggv);
    }
  }

  // fused output row
  const float fl = feats[i * 64 + lane];
  float acc = bo[lane];
  #pragma unroll
  for (int f = 0; f < 64; ++f) {
    acc = fmaf(__shfl(fl, f),   Wo[f * 64 + lane],        acc);
    acc = fmaf(__shfl(aggv, f), Wo[(64 + f) * 64 + lane], acc);
  }
  out[i * 64 + lane] = acc;
}

extern "C" void kernel_launch(void* const* d_in, const int* in_sizes, int n_in,
                              void* d_out, int out_size, void* d_ws, size_t ws_size,
                              hipStream_t stream) {
  const float* x  = (const float*)d_in[0];
  const float* Wf = (const float*)d_in[1];
  const float* bf = (const float*)d_in[2];
  const float* Wl = (const float*)d_in[3];
  const float* bl = (const float*)d_in[4];
  const float* Wo = (const float*)d_in[5];
  const float* bo = (const float*)d_in[6];
  float* out = (float*)d_out;

  char* ws = (char*)d_ws;
  float*     feats    = (float*)(ws);                 // 3,072,000 B
  float*     coords   = (float*)(ws + 3072000);       //   768,000 B
  float*     sqv      = (float*)(ws + 3840000);       //    48,000 B
  _Float16*  coords_h = (_Float16*)(ws + 3888000);    //   384,000 B
  int*       flags    = (int*)(ws + 4272000);         //    48,000 B

  encoder_kernel<<<3000, 256, 0, stream>>>(x, Wf, bf, Wl, bl, feats, coords, coords_h, sqv);
  knn_agg_kernel<<<N_PTS / QB, 512, 0, stream>>>(coords, coords_h, sqv, feats, Wo, bo, out, flags);
  knn_fixup_kernel<<<3000, 256, 0, stream>>>(coords, sqv, feats, flags, Wo, bo, out);
}

// Round 3
// 172.152 us; speedup vs baseline: 1.0127x; 1.0127x over previous
//
#include <hip/hip_runtime.h>
#include <math.h>

typedef unsigned long long u64;
typedef _Float16 f16x8 __attribute__((ext_vector_type(8)));
typedef float f32x16 __attribute__((ext_vector_type(16)));

#define N_PTS 12000
#define KNN 16
#define QB 16                            // queries per block (M rows 0..15 real, 16..31 zero-pad)
#define NWAVES 8                         // waves per block (512 threads)
#define NGROUPS32 (N_PTS / 32)           // 375 candidate groups of 32
#define TAU_PTS 4096
#define TAU_GROUPS32 (TAU_PTS / 32)      // 128 (16 per wave)
#define CAP 384                          // survivor capacity; 6 offers/lane
#define MARGIN 0.08f                     // > 2*m, m = f16 d2 error bound ~0.032
#define EVICT_KEY ((u64)0x7F400000u << 32)  // > any real key and > init sentinels

// ---------------------------------------------------------------------------
// Kernel 1: encoders. feats = tanh(x@Wf+bf); coords = tanh(x@Wl+bl) fp32+f16;
// sq = |coords|^2. One wave per row; 2-way split fma chains for ILP.
// ---------------------------------------------------------------------------
__global__ __launch_bounds__(256) void encoder_kernel(
    const float* __restrict__ x, const float* __restrict__ Wf, const float* __restrict__ bf,
    const float* __restrict__ Wl, const float* __restrict__ bl,
    float* __restrict__ feats, float* __restrict__ coords, _Float16* __restrict__ coords_h,
    float* __restrict__ sq)
{
  const int wave = threadIdx.x >> 6;
  const int lane = threadIdx.x & 63;
  const int i = blockIdx.x * 4 + wave;
  if (i >= N_PTS) return;
  float xv = x[i * 64 + lane];
  float accf0 = bf[lane], accf1 = 0.0f;
  float accc0 = bl[lane & 15], accc1 = 0.0f;
  #pragma unroll
  for (int k = 0; k < 64; k += 2) {
    const float xk0 = __shfl(xv, k);
    const float xk1 = __shfl(xv, k + 1);
    accf0 = fmaf(xk0, Wf[k * 64 + lane], accf0);
    accf1 = fmaf(xk1, Wf[(k + 1) * 64 + lane], accf1);
    accc0 = fmaf(xk0, Wl[k * 16 + (lane & 15)], accc0);
    accc1 = fmaf(xk1, Wl[(k + 1) * 16 + (lane & 15)], accc1);
  }
  feats[i * 64 + lane] = tanhf(accf0 + accf1);
  float c = tanhf(accc0 + accc1);
  float cc = (lane < 16) ? c * c : 0.0f;
  cc += __shfl_xor(cc, 1);
  cc += __shfl_xor(cc, 2);
  cc += __shfl_xor(cc, 4);
  cc += __shfl_xor(cc, 8);
  if (lane < 16) {
    coords[i * 16 + lane] = c;
    coords_h[i * 16 + lane] = (_Float16)c;
  }
  if (lane == 0) sq[i] = cc;
}

// ---------------------------------------------------------------------------
// u64-key helpers. Keys (f32bits(d2)<<32)|j unique; sentinels (0x7F00000t<<32)
// exceed any real key; ~0ull matches no slot.
// ---------------------------------------------------------------------------
__device__ __forceinline__ void ins6(u64 key, u64* k6, u64& kmax) {
  const u64 om = (key < kmax) ? kmax : ~0ull;
  #pragma unroll
  for (int t = 0; t < 6; ++t)
    k6[t] = (k6[t] == om) ? key : k6[t];
  u64 a = k6[0] > k6[1] ? k6[0] : k6[1];
  u64 b = k6[2] > k6[3] ? k6[2] : k6[3];
  u64 c = k6[4] > k6[5] ? k6[4] : k6[5];
  a = a > b ? a : b;
  kmax = a > c ? a : c;
}

__device__ __forceinline__ void ins8(u64 key, u64* k8, u64& kmax) {
  const u64 om = (key < kmax) ? kmax : ~0ull;
  #pragma unroll
  for (int t = 0; t < 8; ++t)
    k8[t] = (k8[t] == om) ? key : k8[t];
  u64 a = k8[0] > k8[1] ? k8[0] : k8[1];
  u64 b = k8[2] > k8[3] ? k8[2] : k8[3];
  u64 c = k8[4] > k8[5] ? k8[4] : k8[5];
  u64 d = k8[6] > k8[7] ? k8[6] : k8[7];
  a = a > b ? a : b;
  c = c > d ? c : d;
  kmax = a > c ? a : c;
}

__device__ __forceinline__ u64 shflx_u64(u64 v, int off) {
  int lo = __shfl_xor((int)(unsigned)v, off);
  int hi = __shfl_xor((int)(unsigned)(v >> 32), off);
  return ((u64)(unsigned)hi << 32) | (unsigned)lo;
}

__device__ __forceinline__ u64 minbfly(u64 m) {
  #pragma unroll
  for (int off = 32; off >= 1; off >>= 1) {
    u64 o = shflx_u64(m, off);
    m = (o < m) ? o : m;
  }
  return m;
}

// compare-and-swap for the 6-element per-lane sort network
#define CAS6(i, j) { const u64 a_ = k6[i], b_ = k6[j]; const bool sw_ = a_ > b_; \
                     k6[i] = sw_ ? b_ : a_; k6[j] = sw_ ? a_ : b_; }

// pipelined group load: 16B f16 coords fragment + sq scalar
#define LOADG(g, uu, ss) { const int jl_ = (g) * 32 + mcol; \
  uu = *(const uint4*)((const char*)coords_h + (size_t)jl_ * 32 + half * 16); \
  ss = sq[jl_]; }

// ---------------------------------------------------------------------------
// Kernel 2: 32x32x16-MFMA KNN + gaussian aggregation + fused output GEMM.
// Block = 16 queries (A rows 0..15 real, 16..31 zero), 8 waves.
// C-INIT TRICK: acc preloaded with -0.5*(sqi+sqj) -> MFMA emits -0.5*d2a;
// gate acc >= -0.5*tau. Dead regs 8..15 stay zero (A rows 16..31 zero).
//
// LATENCY STRUCTURE (round-3): Phases A and B run a 3-deep rotating prefetch
// pipeline (3 group loads in flight; consumed tile was issued 3 iters ago).
// Phase A: 128 sample groups (4096 pts) -> 64 disjoint 64-pt cell minima;
//   tau = 16th order stat + MARGIN (sound: 16 distinct points).
// Phase B: full scan, gate, push u16 survivors (plain per-lane branch).
// Phase C: full-wave exact fp32 re-score per query (ins6, CAP=384 exact),
//   12-CAS per-lane sort, then HALF-WAVE extraction: lane exchanges its
//   sorted 6-list with lane^32 (12 shuffles once) so lanes 0-31 own query
//   s=0 and lanes 32-63 own s=1 as two sorted 6-lists; 16 rounds (not 2x16)
//   of 5-stage u64 butterfly + unique-key owner pop; round results go to a
//   2KB LDS keyS. Gather: full wave per query, 16 batched feats loads.
// Epilogue: block GEMM out = concat(feats,agg)@Wo + bo.
// Only failure mode: survivor overflow -> flag -> fixup recomputes row+out.
// ---------------------------------------------------------------------------
__global__ __launch_bounds__(512, 6) void knn_agg_kernel(
    const float* __restrict__ coords, const _Float16* __restrict__ coords_h,
    const float* __restrict__ sq, const float* __restrict__ feats,
    const float* __restrict__ Wo, const float* __restrict__ bo,
    float* __restrict__ out, int* __restrict__ flags)
{
  __shared__ unsigned short sbuf[QB][CAP];   // 12288 B
  __shared__ int scnt[QB];                   //    64 B
  __shared__ unsigned colminS[QB][64];       //  4096 B
  __shared__ float taugS[QB];                //    64 B
  __shared__ u64 keyS[QB][KNN];              //  2048 B
  __shared__ __align__(16) float featS[QB][64];  // 4096 B
  __shared__ __align__(16) float aggS[QB][64];   // 4096 B

  const int tid = threadIdx.x;       // 0..511
  const int lane = tid & 63;
  const int wave = tid >> 6;         // 0..7
  const int qbase = blockIdx.x * QB;
  const int mcol = lane & 31;        // A row / B col
  const int half = lane >> 5;        // k-half (0: k=0..7, 1: k=8..15)

  if (tid < QB) scnt[tid] = 0;
  #pragma unroll
  for (int t = tid; t < QB * 64; t += 512)
    ((unsigned*)colminS)[t] = 0x7F800000u;   // +INF bits

  // A fragment: A[m=lane&31][k=half*8+j]; rows >=16 zero (padding)
  f16x8 afrag = {0, 0, 0, 0, 0, 0, 0, 0};
  if (mcol < QB) {
    const uint4 u = *(const uint4*)((const char*)coords_h + (qbase + mcol) * 32 + half * 16);
    afrag = __builtin_bit_cast(f16x8, u);
  }
  // rows handled by this lane: row(r) = (r>>2)*8 + 4*half + (r&3), r=0..7
  float nhsqi8[8];
  #pragma unroll
  for (int blk = 0; blk < 2; ++blk) {
    const float4 v = *(const float4*)&sq[qbase + blk * 8 + 4 * half];
    nhsqi8[blk * 4 + 0] = -0.5f * v.x; nhsqi8[blk * 4 + 1] = -0.5f * v.y;
    nhsqi8[blk * 4 + 2] = -0.5f * v.z; nhsqi8[blk * 4 + 3] = -0.5f * v.w;
  }

  f32x16 acc;
  #pragma unroll
  for (int t = 0; t < 16; ++t) acc[t] = 0.0f;   // regs 8..15 stay 0 forever

  __syncthreads();   // scnt + colminS init visible

  // ===================== Phase A: sample scan -> cell minima =================
  // 16 groups per wave (g = wave + 8k, k=0..15), 3-deep prefetch pipeline.
  const int g_self = qbase >> 5;     // the only group that can contain self
  float lmax8[8] = {-INFINITY, -INFINITY, -INFINITY, -INFINITY,
                    -INFINITY, -INFINITY, -INFINITY, -INFINITY};
  {
    uint4 pu0, pu1, pu2; float ps0, ps1, ps2;
    LOADG(wave,                pu0, ps0);
    LOADG(wave + NWAVES,       pu1, ps1);
    LOADG(wave + 2 * NWAVES,   pu2, ps2);
    for (int k = 0; k < 16; ++k) {
      const int g = wave + k * NWAVES;
      const uint4 cu = pu0; const float cs = ps0;
      pu0 = pu1; ps0 = ps1; pu1 = pu2; ps1 = ps2;
      const int kn = k + 3;
      const int gs = (kn < 16) ? (wave + kn * NWAVES) : wave;  // clamp: harmless reload
      LOADG(gs, pu2, ps2);

      const f16x8 bfrag = __builtin_bit_cast(f16x8, cu);
      #pragma unroll
      for (int r = 0; r < 8; ++r) acc[r] = fmaf(-0.5f, cs, nhsqi8[r]);
      acc = __builtin_amdgcn_mfma_f32_32x32x16_f16(afrag, bfrag, acc, 0, 0, 0);
      if (g == g_self) {               // wave-uniform, rare
        #pragma unroll
        for (int r = 0; r < 8; ++r) {
          const int row = (r >> 2) * 8 + 4 * half + (r & 3);
          if (g * 32 + mcol == qbase + row) acc[r] = -INFINITY;  // exclude self
        }
      }
      #pragma unroll
      for (int r = 0; r < 8; ++r) lmax8[r] = fmaxf(lmax8[r], acc[r]);
    }
  }
  {
    // cell = (point col, processing-wave half): disjoint 64-pt subsets of the
    // 4096 samples -> 16 smallest cell minima are 16 distinct points (sound).
    const int cell = mcol * 2 + (wave >> 2);
    #pragma unroll
    for (int r = 0; r < 8; ++r) {
      const int row = (r >> 2) * 8 + 4 * half + (r & 3);
      atomicMin(&colminS[row][cell], __float_as_uint(fmaxf(-2.0f * lmax8[r], 0.0f)));
    }
  }
  __syncthreads();

  // tau per query: 16th order stat of the 64 cell minima (bitonic, lane 15)
  #pragma unroll
  for (int s = 0; s < 2; ++s) {
    const int q = wave * 2 + s;
    float v = __uint_as_float(colminS[q][lane]);
    #pragma unroll
    for (int k = 2; k <= 64; k <<= 1) {
      #pragma unroll
      for (int st = k >> 1; st >= 1; st >>= 1) {
        const float o = __shfl_xor(v, st);
        const bool keepMin = (((lane & st) == 0) == ((lane & k) == 0));
        const float mn = fminf(v, o), mx = fmaxf(v, o);
        v = keepMin ? mn : mx;
      }
    }
    const float tq = __shfl(v, 15) + MARGIN;   // sound gate
    if (lane == 0) taugS[q] = tq;
  }
  __syncthreads();

  // gate in transformed space: d2a <= tau  <=>  acc[r] >= -0.5*tau
  float nht8[8];
  #pragma unroll
  for (int r = 0; r < 8; ++r)
    nht8[r] = -0.5f * taugS[(r >> 2) * 8 + 4 * half + (r & 3)];

  // ===================== Phase B: full MFMA scan, push survivors ============
  {
    uint4 pu0, pu1, pu2; float ps0, ps1, ps2;
    LOADG(wave,                pu0, ps0);
    LOADG(wave + NWAVES,       pu1, ps1);
    LOADG(wave + 2 * NWAVES,   pu2, ps2);
    for (int g = wave; g < NGROUPS32; g += NWAVES) {
      const uint4 cu = pu0; const float cs = ps0;
      pu0 = pu1; ps0 = ps1; pu1 = pu2; ps1 = ps2;
      const int gn = g + 3 * NWAVES;
      const int gs = (gn < NGROUPS32) ? gn : wave;   // clamp: harmless reload
      LOADG(gs, pu2, ps2);

      const f16x8 bfrag = __builtin_bit_cast(f16x8, cu);
      #pragma unroll
      for (int r = 0; r < 8; ++r) acc[r] = fmaf(-0.5f, cs, nhsqi8[r]);
      acc = __builtin_amdgcn_mfma_f32_32x32x16_f16(afrag, bfrag, acc, 0, 0, 0);
      const int j0 = g * 32;
      #pragma unroll
      for (int r = 0; r < 8; ++r) {
        if (acc[r] >= nht8[r]) {       // self passes; filtered in Phase C
          const int row = (r >> 2) * 8 + 4 * half + (r & 3);
          const int p = atomicAdd(&scnt[row], 1);
          if (p < CAP) sbuf[row][p] = (unsigned short)(j0 + mcol);
        }
      }
    }
  }
  __syncthreads();

  // ===================== Phase C: exact fp32 re-score + top-16 ===============
  const int h = lane >> 5;           // which half this lane sits in
  u64 Al[6], Bl[6];                  // post-exchange two sorted 6-lists

  #pragma unroll
  for (int s = 0; s < 2; ++s) {
    const int lq = wave * 2 + s;         // query-in-block 0..15
    const int qg = qbase + lq;           // global query id
    const int cq = scnt[lq];
    const int nread = (cq < CAP) ? cq : CAP;
    const int nit = (nread + 63) >> 6;   // only scan occupied slots

    float ci[16];
    {
      const float4* cp = (const float4*)(coords + qg * 16);
      *(float4*)&ci[0] = cp[0]; *(float4*)&ci[4] = cp[1];
      *(float4*)&ci[8] = cp[2]; *(float4*)&ci[12] = cp[3];
    }
    const float sqiq = sq[qg];

    u64 k6[6];
    #pragma unroll
    for (int t = 0; t < 6; ++t) k6[t] = ((u64)(0x7F000000u + t) << 32);
    u64 kmax6 = ((u64)0x7F000005u << 32);

    for (int t = 0; t < nit; ++t) {      // <=6 offers/lane: no eviction
      const int idx = t * 64 + lane;
      u64 key = ~0ull;
      if (idx < nread) {
        const int jj = sbuf[lq][idx];
        if (jj != qg) {
          const float4* cp = (const float4*)(coords + jj * 16);
          float dot = 0.0f;
          {
            const float4 c0 = cp[0], c1 = cp[1];
            dot = fmaf(ci[0], c0.x, dot); dot = fmaf(ci[1], c0.y, dot);
            dot = fmaf(ci[2], c0.z, dot); dot = fmaf(ci[3], c0.w, dot);
            dot = fmaf(ci[4], c1.x, dot); dot = fmaf(ci[5], c1.y, dot);
            dot = fmaf(ci[6], c1.z, dot); dot = fmaf(ci[7], c1.w, dot);
          }
          {
            const float4 c2 = cp[2], c3 = cp[3];
            dot = fmaf(ci[8],  c2.x, dot); dot = fmaf(ci[9],  c2.y, dot);
            dot = fmaf(ci[10], c2.z, dot); dot = fmaf(ci[11], c2.w, dot);
            dot = fmaf(ci[12], c3.x, dot); dot = fmaf(ci[13], c3.y, dot);
            dot = fmaf(ci[14], c3.z, dot); dot = fmaf(ci[15], c3.w, dot);
          }
          const float d2 = fmaxf(fmaf(-2.0f, dot, sqiq + sq[jj]), 0.0f);
          key = ((u64)__float_as_uint(d2) << 32) | (unsigned)jj;
        }
      }
      ins6(key, k6, kmax6);
    }

    // ---- per-lane ascending sort (12-CAS optimal network for 6 elems) ----
    CAS6(0,5) CAS6(1,3) CAS6(2,4)
    CAS6(1,2) CAS6(3,4)
    CAS6(0,3) CAS6(2,5)
    CAS6(0,1) CAS6(2,3) CAS6(4,5)
    CAS6(1,2) CAS6(3,4)

    // ---- exchange with partner lane (lane^32): the half that owns query s
    // keeps (own list, partner list); full coverage of all 64 rescore lanes.
    #pragma unroll
    for (int t = 0; t < 6; ++t) {
      const u64 p = shflx_u64(k6[t], 32);
      if (h == s) { Al[t] = k6[t]; Bl[t] = p; }
    }
    if (lane == 0) flags[qg] = (cq > CAP);
  }

  // ---- half-wave extraction: 16 rounds serve BOTH queries in parallel ----
  {
    u64 myhead = (Al[0] < Bl[0]) ? Al[0] : Bl[0];
    #pragma unroll
    for (int r = 0; r < KNN; ++r) {
      u64 m = myhead;
      #pragma unroll
      for (int off = 16; off >= 1; off >>= 1) {   // stays within the half
        const u64 o = shflx_u64(m, off);
        m = (o < m) ? o : m;
      }
      if ((lane & 31) == 0) keyS[wave * 2 + h][r] = m;   // lanes 0 and 32
      const bool me = (myhead == m);               // unique: key embeds j
      const bool fa = me && (Al[0] == m);
      const bool fb = me && !fa;
      Al[0] = fa ? Al[1] : Al[0]; Al[1] = fa ? Al[2] : Al[1];
      Al[2] = fa ? Al[3] : Al[2]; Al[3] = fa ? Al[4] : Al[3];
      Al[4] = fa ? Al[5] : Al[4]; Al[5] = fa ? EVICT_KEY : Al[5];
      Bl[0] = fb ? Bl[1] : Bl[0]; Bl[1] = fb ? Bl[2] : Bl[1];
      Bl[2] = fb ? Bl[3] : Bl[2]; Bl[3] = fb ? Bl[4] : Bl[3];
      Bl[4] = fb ? Bl[5] : Bl[4]; Bl[5] = fb ? EVICT_KEY : Bl[5];
      myhead = (Al[0] < Bl[0]) ? Al[0] : Bl[0];
    }
  }

  // ---- aggregation: full wave per query, 16 coalesced gathers batched ----
  // (keyS written by this same wave: only lgkmcnt ordering needed, no barrier)
  #pragma unroll
  for (int s = 0; s < 2; ++s) {
    const int lq = wave * 2 + s;
    const int qg = qbase + lq;
    float aggv = 0.0f;
    #pragma unroll
    for (int r = 0; r < KNN; ++r) {
      const u64 m = keyS[lq][r];
      const float w = __expf(-__uint_as_float((unsigned)(m >> 32)));  // sentinel -> 0
      const int jj = (int)(unsigned)(m & 0xFFFFFFFFull);
      aggv = fmaf(w, feats[jj * 64 + lane], aggv);
    }
    aggS[lq][lane] = aggv;
    featS[lq][lane] = feats[qg * 64 + lane];
  }

  // ===================== Epilogue: fused out GEMM (16 rows/block) ============
  __syncthreads();
  const int row = tid >> 5;        // 0..15
  const int c2 = (tid & 31) * 2;   // cols c2, c2+1 (float2)
  float acc0 = bo[c2], acc1 = bo[c2 + 1];
  #pragma unroll
  for (int f0 = 0; f0 < 64; f0 += 4) {
    const float4 fv = *(const float4*)&featS[row][f0];
    const float4 av = *(const float4*)&aggS[row][f0];
    #pragma unroll
    for (int u = 0; u < 4; ++u) {
      const float fvu = (u == 0) ? fv.x : (u == 1) ? fv.y : (u == 2) ? fv.z : fv.w;
      const float avu = (u == 0) ? av.x : (u == 1) ? av.y : (u == 2) ? av.z : av.w;
      const float2 w0 = *(const float2*)&Wo[(f0 + u) * 64 + c2];
      const float2 w1 = *(const float2*)&Wo[(64 + f0 + u) * 64 + c2];
      acc0 = fmaf(fvu, w0.x, acc0); acc0 = fmaf(avu, w1.x, acc0);
      acc1 = fmaf(fvu, w0.y, acc1); acc1 = fmaf(avu, w1.y, acc1);
    }
  }
  const int orow = qbase + row;
  *(float2*)&out[orow * 64 + c2] = make_float2(acc0, acc1);
}

// ---------------------------------------------------------------------------
// Kernel 2b: exact fallback for flagged (overflowed) queries — expected zero.
// Recomputes the full row: exact KNN + aggregation + fused out row.
// ---------------------------------------------------------------------------
__global__ __launch_bounds__(256) void knn_fixup_kernel(
    const float* __restrict__ coords, const float* __restrict__ sq,
    const float* __restrict__ feats, const int* __restrict__ flags,
    const float* __restrict__ Wo, const float* __restrict__ bo,
    float* __restrict__ out)
{
  const int wave = threadIdx.x >> 6;
  const int lane = threadIdx.x & 63;
  const int i = blockIdx.x * 4 + wave;
  if (i >= N_PTS) return;
  if (!flags[i]) return;
  float ci[16];
  #pragma unroll
  for (int d = 0; d < 16; ++d) ci[d] = coords[i * 16 + d];
  const float sqi = sq[i];

  u64 k8a[8], k8b[8], kmaxA, kmaxB;
  #pragma unroll
  for (int t = 0; t < 8; ++t) {
    k8a[t] = ((u64)(0x7F000000u + t) << 32);
    k8b[t] = ((u64)(0x7F000000u + t) << 32);
  }
  kmaxA = ((u64)0x7F000007u << 32);
  kmaxB = ((u64)0x7F000007u << 32);

  const int niter = (N_PTS + 63) / 64;  // 188
  for (int t = 0; t < niter; ++t) {
    const int j = t * 64 + lane;
    float4 c0 = make_float4(0,0,0,0), c1 = c0, c2 = c0, c3 = c0;
    float sqj = 0.0f;
    if (j < N_PTS) {
      const float4* cp = (const float4*)(coords + j * 16);
      c0 = cp[0]; c1 = cp[1]; c2 = cp[2]; c3 = cp[3];
      sqj = sq[j];
    }
    float dot = ci[0]*c0.x + ci[1]*c0.y + ci[2]*c0.z + ci[3]*c0.w
              + ci[4]*c1.x + ci[5]*c1.y + ci[6]*c1.z + ci[7]*c1.w
              + ci[8]*c2.x + ci[9]*c2.y + ci[10]*c2.z + ci[11]*c2.w
              + ci[12]*c3.x + ci[13]*c3.y + ci[14]*c3.z + ci[15]*c3.w;
    float d2 = fmaxf(fmaf(-2.0f, dot, sqi + sqj), 0.0f);
    const unsigned hi = (j == i || j >= N_PTS) ? 0xFFFFFFFFu : __float_as_uint(d2);
    const u64 key = ((u64)hi << 32) | (unsigned)j;
    if (t & 1) ins8(key, k8a, kmaxA);
    else       ins8(key, k8b, kmaxB);
  }

  u64 tab[16];
  #pragma unroll
  for (int t = 0; t < 8; ++t) { tab[t] = k8a[t]; tab[8 + t] = k8b[t]; }
  u64 lmin = tab[0];
  #pragma unroll
  for (int t = 1; t < 16; ++t) lmin = (tab[t] < lmin) ? tab[t] : lmin;

  float aggv = 0.0f;
  u64 T16 = 0;
  for (int r = 0; r < KNN; ++r) {
    const u64 m = minbfly(lmin);
    if (lmin == m) {
      #pragma unroll
      for (int t = 0; t < 16; ++t) tab[t] = (tab[t] == m) ? ~0ull : tab[t];
      lmin = tab[0];
      #pragma unroll
      for (int t = 1; t < 16; ++t) lmin = (tab[t] < lmin) ? tab[t] : lmin;
    }
    const unsigned hi = (unsigned)(m >> 32);
    const bool ok = hi < 0x7F000000u;
    const float w = ok ? expf(-__uint_as_float(hi)) : 0.0f;
    const int jj = ok ? (int)(unsigned)(m & 0xFFFFFFFFull) : 0;
    aggv = fmaf(w, feats[jj * 64 + lane], aggv);
    T16 = m;
  }

  if (__any((kmaxA < T16) || (kmaxB < T16))) {
    aggv = 0.0f;
    u64 prev = 0;
    for (int r = 0; r < KNN; ++r) {
      u64 best = ~0ull;
      for (int j = lane; j < N_PTS; j += 64) {
        float dot = 0.0f;
        #pragma unroll
        for (int d = 0; d < 16; ++d) dot = fmaf(ci[d], coords[j * 16 + d], dot);
        const float d2 = fmaxf(fmaf(-2.0f, dot, sqi + sq[j]), 0.0f);
        const unsigned hi = (j == i) ? 0xFFFFFFFFu : __float_as_uint(d2);
        const u64 key = ((u64)hi << 32) | (unsigned)j;
        const bool cand = (r == 0) || (key > prev);
        if (cand && key < best) best = key;
      }
      const u64 m = minbfly(best);
      prev = m;
      const unsigned hi = (unsigned)(m >> 32);
      const bool ok = hi < 0x7F000000u;
      const float w = ok ? expf(-__uint_as_float(hi)) : 0.0f;
      const int jj = ok ? (int)(unsigned)(m & 0xFFFFFFFFull) : 0;
      aggv = fmaf(w, feats[jj * 64 + lane], aggv);
    }
  }

  // fused output row
  const float fl = feats[i * 64 + lane];
  float acc = bo[lane];
  #pragma unroll
  for (int f = 0; f < 64; ++f) {
    acc = fmaf(__shfl(fl, f),   Wo[f * 64 + lane],        acc);
    acc = fmaf(__shfl(aggv, f), Wo[(64 + f) * 64 + lane], acc);
  }
  out[i * 64 + lane] = acc;
}

extern "C" void kernel_launch(void* const* d_in, const int* in_sizes, int n_in,
                              void* d_out, int out_size, void* d_ws, size_t ws_size,
                              hipStream_t stream) {
  const float* x  = (const float*)d_in[0];
  const float* Wf = (const float*)d_in[1];
  const float* bf = (const float*)d_in[2];
  const float* Wl = (const float*)d_in[3];
  const float* bl = (const float*)d_in[4];
  const float* Wo = (const float*)d_in[5];
  const float* bo = (const float*)d_in[6];
  float* out = (float*)d_out;

  char* ws = (char*)d_ws;
  float*     feats    = (float*)(ws);                 // 3,072,000 B
  float*     coords   = (float*)(ws + 3072000);       //   768,000 B
  float*     sqv      = (float*)(ws + 3840000);       //    48,000 B
  _Float16*  coords_h = (_Float16*)(ws + 3888000);    //   384,000 B
  int*       flags    = (int*)(ws + 4272000);         //    48,000 B

  encoder_kernel<<<3000, 256, 0, stream>>>(x, Wf, bf, Wl, bl, feats, coords, coords_h, sqv);
  knn_agg_kernel<<<N_PTS / QB, 512, 0, stream>>>(coords, coords_h, sqv, feats, Wo, bo, out, flags);
  knn_fixup_kernel<<<3000, 256, 0, stream>>>(coords, sqv, feats, flags, Wo, bo, out);
}